// Round 10
// baseline (335.002 us; speedup 1.0000x reference)
//
#include <hip/hip_runtime.h>

#define N_NODES 50000
#define N_EDGES 800000
#define F_INPUT 256
#define HDIM 64
#define NCLS 10
#define NGRAPH 64

#define BSHIFT 7                 // 128 nodes per bucket
#define NBUCK 391                // ceil(50000/128)
#define SCAP 4096                // per-bucket stage/eadj capacity (mean 2046, 45 sigma)

// ---------------- pass A: LDS-staged bucket partition ----------------
__global__ __launch_bounds__(256) void k_part(const int* __restrict__ src,
                                              const int* __restrict__ dst,
                                              int* __restrict__ bcnt,
                                              int* __restrict__ stage, int E) {
    __shared__ int cnt[NBUCK];
    __shared__ int base[NBUCK];
    const int tid = threadIdx.x;
    const int e0 = blockIdx.x * 4096;
    int pb[16], pv[16];
    for (int t = tid; t < NBUCK; t += 256) cnt[t] = 0;
    __syncthreads();
#pragma unroll
    for (int j = 0; j < 16; ++j) {
        int e = e0 + j * 256 + tid;
        if (e < E) {
            int s = src[e], d = dst[e];
            pb[j] = d >> BSHIFT;
            pv[j] = (s << BSHIFT) | (d & 127);
            atomicAdd(&cnt[pb[j]], 1);
        } else pb[j] = -1;
    }
    __syncthreads();
    for (int t = tid; t < NBUCK; t += 256) {
        int c = cnt[t];
        base[t] = c ? atomicAdd(&bcnt[t], c) : 0;
        cnt[t] = 0;
    }
    __syncthreads();
#pragma unroll
    for (int j = 0; j < 16; ++j) {
        if (pb[j] >= 0) {
            int r = base[pb[j]] + atomicAdd(&cnt[pb[j]], 1);
            if (r < SCAP) stage[pb[j] * SCAP + r] = pv[j];  // 45-sigma clamp
        }
    }
}

// ---------------- pass B: per-bucket degree + scan + counting sort ----------------
__global__ __launch_bounds__(256) void k_csr(const int* __restrict__ stage,
                                             const int* __restrict__ bcnt,
                                             int* __restrict__ degi,
                                             float* __restrict__ dis,
                                             int* __restrict__ off,
                                             int* __restrict__ eadj, int n) {
    __shared__ int cnt[128];
    __shared__ int loc[128];
    __shared__ int lcur[128];
    __shared__ int ebuf[SCAP];   // 16 KB
    const int b = blockIdx.x;
    const int tid = threadIdx.x;
    const int n0 = b << BSHIFT;
    const int nn = min(128, n - n0);
    const int sb = b * SCAP;
    const int len = min(bcnt[b], SCAP);
    if (tid < 128) cnt[tid] = 0;
    __syncthreads();
    for (int j = tid; j < len; j += 256) atomicAdd(&cnt[stage[sb + j] & 127], 1);
    __syncthreads();
    if (tid < nn) {
        int dg = cnt[tid];
        degi[n0 + tid] = dg;
        dis[n0 + tid] = rsqrtf((float)(dg + 1));
    }
    if (tid < 128) loc[tid] = cnt[tid];
    __syncthreads();
    for (int d = 1; d < 128; d <<= 1) {       // Hillis-Steele inclusive scan
        int x = 0;
        if (tid < 128 && tid >= d) x = loc[tid - d];
        __syncthreads();
        if (tid < 128) loc[tid] += x;
        __syncthreads();
    }
    if (tid < 128) {
        int ex = loc[tid] - cnt[tid];          // exclusive
        if (tid < nn) off[n0 + tid] = sb + ex;
        lcur[tid] = ex;
    }
    __syncthreads();
    for (int j = tid; j < len; j += 256) {
        int p = stage[sb + j];
        int rk = atomicAdd(&lcur[p & 127], 1);
        ebuf[rk] = p >> BSHIFT;
    }
    __syncthreads();
    for (int j = tid; j < len; j += 256) eadj[sb + j] = ebuf[j];  // linear write
}

// ---------------- layer-1 GEMM: split-K x2 via blockIdx.y ----------------
// Proven this round: VGPR 76, no spill. y=0 -> C, y=1 -> C + N*HDIM.
__global__ __launch_bounds__(256) void k_gemm1(const float* __restrict__ A,
                                               const float* __restrict__ B,
                                               float* __restrict__ C, int n) {
    __shared__ float As[64][68];
    __shared__ float Bs[64][64];
    const int tid = threadIdx.x;
    const int row0 = blockIdx.x * 64;
    const int kbase = blockIdx.y * 128;
    const size_t coff = (size_t)blockIdx.y * N_NODES * HDIM;
    const int tx = tid & 15;
    const int ty = tid >> 4;
    const int tr = ty * 4;
    const int tc = tx * 4;
    const int lr = ty;
    const int lk = tx * 4;

    float acc[4][4];
#pragma unroll
    for (int i = 0; i < 4; ++i)
#pragma unroll
        for (int j = 0; j < 4; ++j) acc[i][j] = 0.0f;

    for (int kt = 0; kt < 2; ++kt) {
        const int kc = kbase + kt * 64;
#pragma unroll
        for (int j = 0; j < 4; ++j) {
            int r = lr + 16 * j;
            int grow = row0 + r;
            float4 v = make_float4(0.f, 0.f, 0.f, 0.f);
            if (grow < n) v = *(const float4*)(A + (size_t)grow * F_INPUT + kc + lk);
            *(float4*)&As[r][lk] = v;
        }
#pragma unroll
        for (int j = 0; j < 4; ++j) {
            int kk = lr + 16 * j;
            *(float4*)&Bs[kk][lk] = *(const float4*)(B + (size_t)(kc + kk) * HDIM + lk);
        }
        __syncthreads();
#pragma unroll
        for (int kg = 0; kg < 16; ++kg) {
            float4 b0 = *(const float4*)&Bs[kg * 4 + 0][tc];
            float4 b1 = *(const float4*)&Bs[kg * 4 + 1][tc];
            float4 b2 = *(const float4*)&Bs[kg * 4 + 2][tc];
            float4 b3 = *(const float4*)&Bs[kg * 4 + 3][tc];
#pragma unroll
            for (int i = 0; i < 4; ++i) {
                float4 av = *(const float4*)&As[tr + i][kg * 4];
                acc[i][0] = fmaf(av.x, b0.x, acc[i][0]);
                acc[i][1] = fmaf(av.x, b0.y, acc[i][1]);
                acc[i][2] = fmaf(av.x, b0.z, acc[i][2]);
                acc[i][3] = fmaf(av.x, b0.w, acc[i][3]);
                acc[i][0] = fmaf(av.y, b1.x, acc[i][0]);
                acc[i][1] = fmaf(av.y, b1.y, acc[i][1]);
                acc[i][2] = fmaf(av.y, b1.z, acc[i][2]);
                acc[i][3] = fmaf(av.y, b1.w, acc[i][3]);
                acc[i][0] = fmaf(av.z, b2.x, acc[i][0]);
                acc[i][1] = fmaf(av.z, b2.y, acc[i][1]);
                acc[i][2] = fmaf(av.z, b2.z, acc[i][2]);
                acc[i][3] = fmaf(av.z, b2.w, acc[i][3]);
                acc[i][0] = fmaf(av.w, b3.x, acc[i][0]);
                acc[i][1] = fmaf(av.w, b3.y, acc[i][1]);
                acc[i][2] = fmaf(av.w, b3.z, acc[i][2]);
                acc[i][3] = fmaf(av.w, b3.w, acc[i][3]);
            }
        }
        __syncthreads();
    }
#pragma unroll
    for (int i = 0; i < 4; ++i) {
        int grow = row0 + tr + i;
        if (grow < n) {
            *(float4*)(C + coff + (size_t)grow * HDIM + tc) =
                make_float4(acc[i][0], acc[i][1], acc[i][2], acc[i][3]);
        }
    }
}

// ---------------- layers 2/3 GEMM: round-2/4 proven body verbatim ----------------
// (VGPR 68 measured, zero bank conflicts). NOT shared with k_gemm1: the
// KTILES=1 template instantiation with runtime coff spilled to VGPR 256
// (round 9 counters: WRITE +3MB scratch, 50us vs 13).
template <int K>
__global__ __launch_bounds__(256) void k_gemm64(const float* __restrict__ A,
                                                const float* __restrict__ B,
                                                float* __restrict__ C, int n) {
    __shared__ float As[64][68];
    __shared__ float Bs[64][64];
    const int tid = threadIdx.x;
    const int row0 = blockIdx.x * 64;
    const int tx = tid & 15;
    const int ty = tid >> 4;
    const int tr = ty * 4;
    const int tc = tx * 4;
    const int lr = ty;
    const int lk = tx * 4;

    float acc[4][4];
#pragma unroll
    for (int i = 0; i < 4; ++i)
#pragma unroll
        for (int j = 0; j < 4; ++j) acc[i][j] = 0.0f;

    for (int kc = 0; kc < K; kc += 64) {
#pragma unroll
        for (int j = 0; j < 4; ++j) {
            int r = lr + 16 * j;
            int grow = row0 + r;
            float4 v = make_float4(0.f, 0.f, 0.f, 0.f);
            if (grow < n) v = *(const float4*)(A + (size_t)grow * K + kc + lk);
            *(float4*)&As[r][lk] = v;
        }
#pragma unroll
        for (int j = 0; j < 4; ++j) {
            int kk = lr + 16 * j;
            *(float4*)&Bs[kk][lk] = *(const float4*)(B + (size_t)(kc + kk) * HDIM + lk);
        }
        __syncthreads();
#pragma unroll
        for (int kg = 0; kg < 16; ++kg) {
            float4 b0 = *(const float4*)&Bs[kg * 4 + 0][tc];
            float4 b1 = *(const float4*)&Bs[kg * 4 + 1][tc];
            float4 b2 = *(const float4*)&Bs[kg * 4 + 2][tc];
            float4 b3 = *(const float4*)&Bs[kg * 4 + 3][tc];
#pragma unroll
            for (int i = 0; i < 4; ++i) {
                float4 av = *(const float4*)&As[tr + i][kg * 4];
                acc[i][0] = fmaf(av.x, b0.x, acc[i][0]);
                acc[i][1] = fmaf(av.x, b0.y, acc[i][1]);
                acc[i][2] = fmaf(av.x, b0.z, acc[i][2]);
                acc[i][3] = fmaf(av.x, b0.w, acc[i][3]);
                acc[i][0] = fmaf(av.y, b1.x, acc[i][0]);
                acc[i][1] = fmaf(av.y, b1.y, acc[i][1]);
                acc[i][2] = fmaf(av.y, b1.z, acc[i][2]);
                acc[i][3] = fmaf(av.y, b1.w, acc[i][3]);
                acc[i][0] = fmaf(av.z, b2.x, acc[i][0]);
                acc[i][1] = fmaf(av.z, b2.y, acc[i][1]);
                acc[i][2] = fmaf(av.z, b2.z, acc[i][2]);
                acc[i][3] = fmaf(av.z, b2.w, acc[i][3]);
                acc[i][0] = fmaf(av.w, b3.x, acc[i][0]);
                acc[i][1] = fmaf(av.w, b3.y, acc[i][1]);
                acc[i][2] = fmaf(av.w, b3.z, acc[i][2]);
                acc[i][3] = fmaf(av.w, b3.w, acc[i][3]);
            }
        }
        __syncthreads();
    }
#pragma unroll
    for (int i = 0; i < 4; ++i) {
        int grow = row0 + tr + i;
        if (grow < n) {
            *(float4*)(C + (size_t)grow * HDIM + tc) =
                make_float4(acc[i][0], acc[i][1], acc[i][2], acc[i][3]);
        }
    }
}

// ---------------- split-K reduction: a += b (float4) ----------------
__global__ __launch_bounds__(256) void k_sum(float4* __restrict__ a,
                                             const float4* __restrict__ b, int n4) {
    int i = blockIdx.x * 256 + threadIdx.x;
    if (i < n4) {
        float4 x = a[i], y = b[i];
        a[i] = make_float4(x.x + y.x, x.y + y.y, x.z + y.z, x.w + y.w);
    }
}

// ---------------- pull aggregation + self-loop + bias + relu ----------------
__global__ __launch_bounds__(256) void k_gather(const float* __restrict__ h,
                                                const int* __restrict__ off,
                                                const int* __restrict__ degi,
                                                const int* __restrict__ eadj,
                                                const float* __restrict__ dis,
                                                const float* __restrict__ bias,
                                                float* __restrict__ out, int n) {
    int t = blockIdx.x * 256 + threadIdx.x;
    int i = t >> 4;
    if (i >= n) return;
    int q = (t & 15) * 4;
    float di = dis[i];
    int e0 = off[i];
    int e1 = e0 + degi[i];
    float ax = 0.f, ay = 0.f, az = 0.f, aw = 0.f;
    float bx = 0.f, by = 0.f, bz = 0.f, bw = 0.f;
    int e = e0;
    for (; e + 1 < e1; e += 2) {       // unroll x2: two row loads in flight
        int s0 = eadj[e];
        int s1 = eadj[e + 1];
        float4 v0 = *(const float4*)(h + (size_t)s0 * HDIM + q);
        float4 v1 = *(const float4*)(h + (size_t)s1 * HDIM + q);
        float w0 = dis[s0] * di;
        float w1 = dis[s1] * di;
        ax = fmaf(v0.x, w0, ax); ay = fmaf(v0.y, w0, ay);
        az = fmaf(v0.z, w0, az); aw = fmaf(v0.w, w0, aw);
        bx = fmaf(v1.x, w1, bx); by = fmaf(v1.y, w1, by);
        bz = fmaf(v1.z, w1, bz); bw = fmaf(v1.w, w1, bw);
    }
    if (e < e1) {
        int s0 = eadj[e];
        float4 v0 = *(const float4*)(h + (size_t)s0 * HDIM + q);
        float w0 = dis[s0] * di;
        ax = fmaf(v0.x, w0, ax); ay = fmaf(v0.y, w0, ay);
        az = fmaf(v0.z, w0, az); aw = fmaf(v0.w, w0, aw);
    }
    ax += bx; ay += by; az += bz; aw += bw;
    float sn = di * di;                // self-loop weight = 1/(deg+1)
    float4 hv = *(const float4*)(h + (size_t)i * HDIM + q);
    float4 b = *(const float4*)(bias + q);
    ax = fmaf(hv.x, sn, ax) + b.x;
    ay = fmaf(hv.y, sn, ay) + b.y;
    az = fmaf(hv.z, sn, az) + b.z;
    aw = fmaf(hv.w, sn, aw) + b.w;
    *(float4*)(out + (size_t)i * HDIM + q) =
        make_float4(fmaxf(ax, 0.f), fmaxf(ay, 0.f), fmaxf(az, 0.f), fmaxf(aw, 0.f));
}

// ---------------- pool phase 1: partial sums, 8 segments per graph ----------------
__global__ __launch_bounds__(256) void k_pool_acc(const float* __restrict__ h,
                                                  const int* __restrict__ batch,
                                                  float* __restrict__ pooled, int n) {
    __shared__ float part[4][64];
    int g = blockIdx.x >> 3;
    int seg = blockIdx.x & 7;
    int t = threadIdx.x;
    int f = t & 63;
    int rg = t >> 6;
    int lo = 0, hi = n;
    while (lo < hi) { int m = (lo + hi) >> 1; if (batch[m] < g) lo = m + 1; else hi = m; }
    int s = lo;
    lo = 0; hi = n;
    while (lo < hi) { int m = (lo + hi) >> 1; if (batch[m] < g + 1) lo = m + 1; else hi = m; }
    int e2 = lo;
    int len = e2 - s;
    int chunk = (len + 7) >> 3;
    int i0 = s + seg * chunk;
    int i1 = min(i0 + chunk, e2);

    float sum = 0.f;
    for (int i = i0 + rg; i < i1; i += 4) sum += h[(size_t)i * HDIM + f];
    part[rg][f] = sum;
    __syncthreads();
    if (t < 64) {
        float tot = part[0][t] + part[1][t] + part[2][t] + part[3][t];
        if (tot != 0.f) atomicAdd(&pooled[g * HDIM + t], tot);
    }
}

// ---------------- pool phase 2: mean + linear head ----------------
__global__ __launch_bounds__(640) void k_head(const float* __restrict__ pooled,
                                              const int* __restrict__ batch,
                                              const float* __restrict__ linW,
                                              const float* __restrict__ linb,
                                              float* __restrict__ out, int n) {
    int t = threadIdx.x;
    if (t >= NGRAPH * NCLS) return;
    int g = t / NCLS;
    int c = t - g * NCLS;
    int lo = 0, hi = n;
    while (lo < hi) { int m = (lo + hi) >> 1; if (batch[m] < g) lo = m + 1; else hi = m; }
    int s = lo;
    lo = 0; hi = n;
    while (lo < hi) { int m = (lo + hi) >> 1; if (batch[m] < g + 1) lo = m + 1; else hi = m; }
    float inv = 1.0f / fmaxf((float)(lo - s), 1.0f);
    float acc = linb[c];
#pragma unroll
    for (int k = 0; k < HDIM; ++k)
        acc = fmaf(pooled[g * HDIM + k] * inv, linW[k * NCLS + c], acc);
    out[g * NCLS + c] = acc;
}

extern "C" void kernel_launch(void* const* d_in, const int* in_sizes, int n_in,
                              void* d_out, int out_size, void* d_ws, size_t ws_size,
                              hipStream_t stream) {
    (void)in_sizes; (void)n_in; (void)out_size; (void)ws_size;
    const float* x    = (const float*)d_in[0];
    const int*   ei   = (const int*)d_in[1];
    const int*   batch= (const int*)d_in[2];
    const float* W1   = (const float*)d_in[3];
    const float* b1   = (const float*)d_in[4];
    const float* W2   = (const float*)d_in[5];
    const float* b2   = (const float*)d_in[6];
    const float* W3   = (const float*)d_in[7];
    const float* b3   = (const float*)d_in[8];
    const float* linW = (const float*)d_in[9];
    const float* linb = (const float*)d_in[10];
    float* out = (float*)d_out;

    const int N = N_NODES, E = N_EDGES;
    const int* src = ei;
    const int* dst = ei + E;

    char* ws = (char*)d_ws;
    float* hA     = (float*)ws; ws += (size_t)N * HDIM * 4;
    float* hB     = (float*)ws; ws += (size_t)N * HDIM * 4;   // contiguous after hA (split-K)
    float* dis    = (float*)ws; ws += (size_t)N * 4;
    int*   eadj   = (int*)ws;   ws += (size_t)NBUCK * SCAP * 4;
    int*   stage  = (int*)ws;   ws += (size_t)NBUCK * SCAP * 4;
    int*   degi   = (int*)ws;   ws += (size_t)N * 4;
    int*   off    = (int*)ws;   ws += (size_t)N * 4;
    int*   bcnt   = (int*)ws;   ws += (size_t)NBUCK * 4;
    float* pooled = (float*)ws; ws += (size_t)NGRAPH * HDIM * 4;

    const int nbE = (E + 4095) / 4096;  // 196
    const int gb  = (N + 63) / 64;      // 782
    const int ngth = (N * 16 + 255) / 256;

    hipMemsetAsync(bcnt, 0, (size_t)NBUCK * 4, stream);
    hipMemsetAsync(pooled, 0, (size_t)NGRAPH * HDIM * 4, stream);
    k_part<<<nbE, 256, 0, stream>>>(src, dst, bcnt, stage, E);
    k_csr<<<NBUCK, 256, 0, stream>>>(stage, bcnt, degi, dis, off, eadj, N);

    // layer 1: split-K x2 (y=0 -> hA, y=1 -> hB), then hA += hB
    k_gemm1<<<dim3(gb, 2), 256, 0, stream>>>(x, W1, hA, N);
    k_sum<<<(N * HDIM / 4 + 255) / 256, 256, 0, stream>>>((float4*)hA, (const float4*)hB,
                                                          N * HDIM / 4);
    k_gather<<<ngth, 256, 0, stream>>>(hA, off, degi, eadj, dis, b1, hB, N);
    // layer 2
    k_gemm64<HDIM><<<gb, 256, 0, stream>>>(hB, W2, hA, N);
    k_gather<<<ngth, 256, 0, stream>>>(hA, off, degi, eadj, dis, b2, hB, N);
    // layer 3
    k_gemm64<HDIM><<<gb, 256, 0, stream>>>(hB, W3, hA, N);
    k_gather<<<ngth, 256, 0, stream>>>(hA, off, degi, eadj, dis, b3, hB, N);
    // pool + head
    k_pool_acc<<<NGRAPH * 8, 256, 0, stream>>>(hB, batch, pooled, N);
    k_head<<<1, 640, 0, stream>>>(pooled, batch, linW, linb, out, N);
}

// Round 11
// 315.154 us; speedup vs baseline: 1.0630x; 1.0630x over previous
//
#include <hip/hip_runtime.h>

#define N_NODES 50000
#define N_EDGES 800000
#define F_INPUT 256
#define HDIM 64
#define NCLS 10
#define NGRAPH 64

#define BSHIFT 7                 // 128 nodes per bucket
#define NBUCK 391                // ceil(50000/128)
#define SCAP 4096                // per-bucket stage/eadj capacity (mean 2046, 45 sigma)

// ---------------- pass A: LDS-staged bucket partition ----------------
__global__ __launch_bounds__(256) void k_part(const int* __restrict__ src,
                                              const int* __restrict__ dst,
                                              int* __restrict__ bcnt,
                                              int* __restrict__ stage, int E) {
    __shared__ int cnt[NBUCK];
    __shared__ int base[NBUCK];
    const int tid = threadIdx.x;
    const int e0 = blockIdx.x * 4096;
    int pb[16], pv[16];
    for (int t = tid; t < NBUCK; t += 256) cnt[t] = 0;
    __syncthreads();
#pragma unroll
    for (int j = 0; j < 16; ++j) {
        int e = e0 + j * 256 + tid;
        if (e < E) {
            int s = src[e], d = dst[e];
            pb[j] = d >> BSHIFT;
            pv[j] = (s << BSHIFT) | (d & 127);
            atomicAdd(&cnt[pb[j]], 1);
        } else pb[j] = -1;
    }
    __syncthreads();
    for (int t = tid; t < NBUCK; t += 256) {
        int c = cnt[t];
        base[t] = c ? atomicAdd(&bcnt[t], c) : 0;
        cnt[t] = 0;
    }
    __syncthreads();
#pragma unroll
    for (int j = 0; j < 16; ++j) {
        if (pb[j] >= 0) {
            int r = base[pb[j]] + atomicAdd(&cnt[pb[j]], 1);
            if (r < SCAP) stage[pb[j] * SCAP + r] = pv[j];  // 45-sigma clamp
        }
    }
}

// ---------------- pass B: per-bucket degree + scan + counting sort ----------------
__global__ __launch_bounds__(256) void k_csr(const int* __restrict__ stage,
                                             const int* __restrict__ bcnt,
                                             int* __restrict__ degi,
                                             float* __restrict__ dis,
                                             int* __restrict__ off,
                                             int* __restrict__ eadj, int n) {
    __shared__ int cnt[128];
    __shared__ int loc[128];
    __shared__ int lcur[128];
    __shared__ int ebuf[SCAP];   // 16 KB
    const int b = blockIdx.x;
    const int tid = threadIdx.x;
    const int n0 = b << BSHIFT;
    const int nn = min(128, n - n0);
    const int sb = b * SCAP;
    const int len = min(bcnt[b], SCAP);
    if (tid < 128) cnt[tid] = 0;
    __syncthreads();
    for (int j = tid; j < len; j += 256) atomicAdd(&cnt[stage[sb + j] & 127], 1);
    __syncthreads();
    if (tid < nn) {
        int dg = cnt[tid];
        degi[n0 + tid] = dg;
        dis[n0 + tid] = rsqrtf((float)(dg + 1));
    }
    if (tid < 128) loc[tid] = cnt[tid];
    __syncthreads();
    for (int d = 1; d < 128; d <<= 1) {       // Hillis-Steele inclusive scan
        int x = 0;
        if (tid < 128 && tid >= d) x = loc[tid - d];
        __syncthreads();
        if (tid < 128) loc[tid] += x;
        __syncthreads();
    }
    if (tid < 128) {
        int ex = loc[tid] - cnt[tid];          // exclusive
        if (tid < nn) off[n0 + tid] = sb + ex;
        lcur[tid] = ex;
    }
    __syncthreads();
    for (int j = tid; j < len; j += 256) {
        int p = stage[sb + j];
        int rk = atomicAdd(&lcur[p & 127], 1);
        ebuf[rk] = p >> BSHIFT;
    }
    __syncthreads();
    for (int j = tid; j < len; j += 256) eadj[sb + j] = ebuf[j];  // linear write
}

// ---------------- layer-1 GEMM: split-K x2 via blockIdx.y ----------------
// Measured round 9: VGPR 76, no spill, 50us. y=0 -> C, y=1 -> C + N*HDIM.
__global__ __launch_bounds__(256) void k_gemm1(const float* __restrict__ A,
                                               const float* __restrict__ B,
                                               float* __restrict__ C, int n) {
    __shared__ float As[64][68];
    __shared__ float Bs[64][64];
    const int tid = threadIdx.x;
    const int row0 = blockIdx.x * 64;
    const int kbase = blockIdx.y * 128;
    const size_t coff = (size_t)blockIdx.y * N_NODES * HDIM;
    const int tx = tid & 15;
    const int ty = tid >> 4;
    const int tr = ty * 4;
    const int tc = tx * 4;
    const int lr = ty;
    const int lk = tx * 4;

    float acc[4][4];
#pragma unroll
    for (int i = 0; i < 4; ++i)
#pragma unroll
        for (int j = 0; j < 4; ++j) acc[i][j] = 0.0f;

    for (int kt = 0; kt < 2; ++kt) {
        const int kc = kbase + kt * 64;
#pragma unroll
        for (int j = 0; j < 4; ++j) {
            int r = lr + 16 * j;
            int grow = row0 + r;
            float4 v = make_float4(0.f, 0.f, 0.f, 0.f);
            if (grow < n) v = *(const float4*)(A + (size_t)grow * F_INPUT + kc + lk);
            *(float4*)&As[r][lk] = v;
        }
#pragma unroll
        for (int j = 0; j < 4; ++j) {
            int kk = lr + 16 * j;
            *(float4*)&Bs[kk][lk] = *(const float4*)(B + (size_t)(kc + kk) * HDIM + lk);
        }
        __syncthreads();
#pragma unroll
        for (int kg = 0; kg < 16; ++kg) {
            float4 b0 = *(const float4*)&Bs[kg * 4 + 0][tc];
            float4 b1 = *(const float4*)&Bs[kg * 4 + 1][tc];
            float4 b2 = *(const float4*)&Bs[kg * 4 + 2][tc];
            float4 b3 = *(const float4*)&Bs[kg * 4 + 3][tc];
#pragma unroll
            for (int i = 0; i < 4; ++i) {
                float4 av = *(const float4*)&As[tr + i][kg * 4];
                acc[i][0] = fmaf(av.x, b0.x, acc[i][0]);
                acc[i][1] = fmaf(av.x, b0.y, acc[i][1]);
                acc[i][2] = fmaf(av.x, b0.z, acc[i][2]);
                acc[i][3] = fmaf(av.x, b0.w, acc[i][3]);
                acc[i][0] = fmaf(av.y, b1.x, acc[i][0]);
                acc[i][1] = fmaf(av.y, b1.y, acc[i][1]);
                acc[i][2] = fmaf(av.y, b1.z, acc[i][2]);
                acc[i][3] = fmaf(av.y, b1.w, acc[i][3]);
                acc[i][0] = fmaf(av.z, b2.x, acc[i][0]);
                acc[i][1] = fmaf(av.z, b2.y, acc[i][1]);
                acc[i][2] = fmaf(av.z, b2.z, acc[i][2]);
                acc[i][3] = fmaf(av.z, b2.w, acc[i][3]);
                acc[i][0] = fmaf(av.w, b3.x, acc[i][0]);
                acc[i][1] = fmaf(av.w, b3.y, acc[i][1]);
                acc[i][2] = fmaf(av.w, b3.z, acc[i][2]);
                acc[i][3] = fmaf(av.w, b3.w, acc[i][3]);
            }
        }
        __syncthreads();
    }
#pragma unroll
    for (int i = 0; i < 4; ++i) {
        int grow = row0 + tr + i;
        if (grow < n) {
            *(float4*)(C + coff + (size_t)grow * HDIM + tc) =
                make_float4(acc[i][0], acc[i][1], acc[i][2], acc[i][3]);
        }
    }
}

// ---------------- layers 2/3 GEMM: K=64, RUNTIME trip count ----------------
// Round 10 diagnosis: the compile-time K=64 template (single-trip kc loop)
// gets fully flattened; the pipeliner merges staging + 16x-unrolled kg loop
// into one straight-line region and spills (VGPR 256, ~50us — every round
// since r2). Runtime `ktn` (=1) makes the trip count opaque -> loop stays a
// loop -> live set bounded like k_gemm1 (76 VGPR).
__global__ __launch_bounds__(256) void k_gemm2(const float* __restrict__ A,
                                               const float* __restrict__ B,
                                               float* __restrict__ C, int n, int ktn) {
    __shared__ float As[64][68];
    __shared__ float Bs[64][64];
    const int tid = threadIdx.x;
    const int row0 = blockIdx.x * 64;
    const int tx = tid & 15;
    const int ty = tid >> 4;
    const int tr = ty * 4;
    const int tc = tx * 4;
    const int lr = ty;
    const int lk = tx * 4;

    float acc[4][4];
#pragma unroll
    for (int i = 0; i < 4; ++i)
#pragma unroll
        for (int j = 0; j < 4; ++j) acc[i][j] = 0.0f;

    for (int kt = 0; kt < ktn; ++kt) {
        const int kc = kt * 64;
#pragma unroll
        for (int j = 0; j < 4; ++j) {
            int r = lr + 16 * j;
            int grow = row0 + r;
            float4 v = make_float4(0.f, 0.f, 0.f, 0.f);
            if (grow < n) v = *(const float4*)(A + (size_t)grow * HDIM + kc + lk);
            *(float4*)&As[r][lk] = v;
        }
#pragma unroll
        for (int j = 0; j < 4; ++j) {
            int kk = lr + 16 * j;
            *(float4*)&Bs[kk][lk] = *(const float4*)(B + (size_t)(kc + kk) * HDIM + lk);
        }
        __syncthreads();
#pragma unroll
        for (int kg = 0; kg < 16; ++kg) {
            float4 b0 = *(const float4*)&Bs[kg * 4 + 0][tc];
            float4 b1 = *(const float4*)&Bs[kg * 4 + 1][tc];
            float4 b2 = *(const float4*)&Bs[kg * 4 + 2][tc];
            float4 b3 = *(const float4*)&Bs[kg * 4 + 3][tc];
#pragma unroll
            for (int i = 0; i < 4; ++i) {
                float4 av = *(const float4*)&As[tr + i][kg * 4];
                acc[i][0] = fmaf(av.x, b0.x, acc[i][0]);
                acc[i][1] = fmaf(av.x, b0.y, acc[i][1]);
                acc[i][2] = fmaf(av.x, b0.z, acc[i][2]);
                acc[i][3] = fmaf(av.x, b0.w, acc[i][3]);
                acc[i][0] = fmaf(av.y, b1.x, acc[i][0]);
                acc[i][1] = fmaf(av.y, b1.y, acc[i][1]);
                acc[i][2] = fmaf(av.y, b1.z, acc[i][2]);
                acc[i][3] = fmaf(av.y, b1.w, acc[i][3]);
                acc[i][0] = fmaf(av.z, b2.x, acc[i][0]);
                acc[i][1] = fmaf(av.z, b2.y, acc[i][1]);
                acc[i][2] = fmaf(av.z, b2.z, acc[i][2]);
                acc[i][3] = fmaf(av.z, b2.w, acc[i][3]);
                acc[i][0] = fmaf(av.w, b3.x, acc[i][0]);
                acc[i][1] = fmaf(av.w, b3.y, acc[i][1]);
                acc[i][2] = fmaf(av.w, b3.z, acc[i][2]);
                acc[i][3] = fmaf(av.w, b3.w, acc[i][3]);
            }
        }
        __syncthreads();
    }
#pragma unroll
    for (int i = 0; i < 4; ++i) {
        int grow = row0 + tr + i;
        if (grow < n) {
            *(float4*)(C + (size_t)grow * HDIM + tc) =
                make_float4(acc[i][0], acc[i][1], acc[i][2], acc[i][3]);
        }
    }
}

// ---------------- split-K reduction: a += b (float4) ----------------
__global__ __launch_bounds__(256) void k_sum(float4* __restrict__ a,
                                             const float4* __restrict__ b, int n4) {
    int i = blockIdx.x * 256 + threadIdx.x;
    if (i < n4) {
        float4 x = a[i], y = b[i];
        a[i] = make_float4(x.x + y.x, x.y + y.y, x.z + y.z, x.w + y.w);
    }
}

// ---------------- pull aggregation + self-loop + bias + relu ----------------
__global__ __launch_bounds__(256) void k_gather(const float* __restrict__ h,
                                                const int* __restrict__ off,
                                                const int* __restrict__ degi,
                                                const int* __restrict__ eadj,
                                                const float* __restrict__ dis,
                                                const float* __restrict__ bias,
                                                float* __restrict__ out, int n) {
    int t = blockIdx.x * 256 + threadIdx.x;
    int i = t >> 4;
    if (i >= n) return;
    int q = (t & 15) * 4;
    float di = dis[i];
    int e0 = off[i];
    int e1 = e0 + degi[i];
    float ax = 0.f, ay = 0.f, az = 0.f, aw = 0.f;
    float bx = 0.f, by = 0.f, bz = 0.f, bw = 0.f;
    int e = e0;
    for (; e + 1 < e1; e += 2) {       // unroll x2: two row loads in flight
        int s0 = eadj[e];
        int s1 = eadj[e + 1];
        float4 v0 = *(const float4*)(h + (size_t)s0 * HDIM + q);
        float4 v1 = *(const float4*)(h + (size_t)s1 * HDIM + q);
        float w0 = dis[s0] * di;
        float w1 = dis[s1] * di;
        ax = fmaf(v0.x, w0, ax); ay = fmaf(v0.y, w0, ay);
        az = fmaf(v0.z, w0, az); aw = fmaf(v0.w, w0, aw);
        bx = fmaf(v1.x, w1, bx); by = fmaf(v1.y, w1, by);
        bz = fmaf(v1.z, w1, bz); bw = fmaf(v1.w, w1, bw);
    }
    if (e < e1) {
        int s0 = eadj[e];
        float4 v0 = *(const float4*)(h + (size_t)s0 * HDIM + q);
        float w0 = dis[s0] * di;
        ax = fmaf(v0.x, w0, ax); ay = fmaf(v0.y, w0, ay);
        az = fmaf(v0.z, w0, az); aw = fmaf(v0.w, w0, aw);
    }
    ax += bx; ay += by; az += bz; aw += bw;
    float sn = di * di;                // self-loop weight = 1/(deg+1)
    float4 hv = *(const float4*)(h + (size_t)i * HDIM + q);
    float4 b = *(const float4*)(bias + q);
    ax = fmaf(hv.x, sn, ax) + b.x;
    ay = fmaf(hv.y, sn, ay) + b.y;
    az = fmaf(hv.z, sn, az) + b.z;
    aw = fmaf(hv.w, sn, aw) + b.w;
    *(float4*)(out + (size_t)i * HDIM + q) =
        make_float4(fmaxf(ax, 0.f), fmaxf(ay, 0.f), fmaxf(az, 0.f), fmaxf(aw, 0.f));
}

// ---------------- pool phase 1: partial sums, 8 segments per graph ----------------
__global__ __launch_bounds__(256) void k_pool_acc(const float* __restrict__ h,
                                                  const int* __restrict__ batch,
                                                  float* __restrict__ pooled, int n) {
    __shared__ float part[4][64];
    int g = blockIdx.x >> 3;
    int seg = blockIdx.x & 7;
    int t = threadIdx.x;
    int f = t & 63;
    int rg = t >> 6;
    int lo = 0, hi = n;
    while (lo < hi) { int m = (lo + hi) >> 1; if (batch[m] < g) lo = m + 1; else hi = m; }
    int s = lo;
    lo = 0; hi = n;
    while (lo < hi) { int m = (lo + hi) >> 1; if (batch[m] < g + 1) lo = m + 1; else hi = m; }
    int e2 = lo;
    int len = e2 - s;
    int chunk = (len + 7) >> 3;
    int i0 = s + seg * chunk;
    int i1 = min(i0 + chunk, e2);

    float sum = 0.f;
    for (int i = i0 + rg; i < i1; i += 4) sum += h[(size_t)i * HDIM + f];
    part[rg][f] = sum;
    __syncthreads();
    if (t < 64) {
        float tot = part[0][t] + part[1][t] + part[2][t] + part[3][t];
        if (tot != 0.f) atomicAdd(&pooled[g * HDIM + t], tot);
    }
}

// ---------------- pool phase 2: mean + linear head ----------------
__global__ __launch_bounds__(640) void k_head(const float* __restrict__ pooled,
                                              const int* __restrict__ batch,
                                              const float* __restrict__ linW,
                                              const float* __restrict__ linb,
                                              float* __restrict__ out, int n) {
    int t = threadIdx.x;
    if (t >= NGRAPH * NCLS) return;
    int g = t / NCLS;
    int c = t - g * NCLS;
    int lo = 0, hi = n;
    while (lo < hi) { int m = (lo + hi) >> 1; if (batch[m] < g) lo = m + 1; else hi = m; }
    int s = lo;
    lo = 0; hi = n;
    while (lo < hi) { int m = (lo + hi) >> 1; if (batch[m] < g + 1) lo = m + 1; else hi = m; }
    float inv = 1.0f / fmaxf((float)(lo - s), 1.0f);
    float acc = linb[c];
#pragma unroll
    for (int k = 0; k < HDIM; ++k)
        acc = fmaf(pooled[g * HDIM + k] * inv, linW[k * NCLS + c], acc);
    out[g * NCLS + c] = acc;
}

extern "C" void kernel_launch(void* const* d_in, const int* in_sizes, int n_in,
                              void* d_out, int out_size, void* d_ws, size_t ws_size,
                              hipStream_t stream) {
    (void)in_sizes; (void)n_in; (void)out_size; (void)ws_size;
    const float* x    = (const float*)d_in[0];
    const int*   ei   = (const int*)d_in[1];
    const int*   batch= (const int*)d_in[2];
    const float* W1   = (const float*)d_in[3];
    const float* b1   = (const float*)d_in[4];
    const float* W2   = (const float*)d_in[5];
    const float* b2   = (const float*)d_in[6];
    const float* W3   = (const float*)d_in[7];
    const float* b3   = (const float*)d_in[8];
    const float* linW = (const float*)d_in[9];
    const float* linb = (const float*)d_in[10];
    float* out = (float*)d_out;

    const int N = N_NODES, E = N_EDGES;
    const int* src = ei;
    const int* dst = ei + E;

    char* ws = (char*)d_ws;
    float* hA     = (float*)ws; ws += (size_t)N * HDIM * 4;
    float* hB     = (float*)ws; ws += (size_t)N * HDIM * 4;   // contiguous after hA (split-K)
    float* dis    = (float*)ws; ws += (size_t)N * 4;
    int*   eadj   = (int*)ws;   ws += (size_t)NBUCK * SCAP * 4;
    int*   stage  = (int*)ws;   ws += (size_t)NBUCK * SCAP * 4;
    int*   degi   = (int*)ws;   ws += (size_t)N * 4;
    int*   off    = (int*)ws;   ws += (size_t)N * 4;
    int*   bcnt   = (int*)ws;   ws += (size_t)NBUCK * 4;
    float* pooled = (float*)ws; ws += (size_t)NGRAPH * HDIM * 4;

    const int nbE = (E + 4095) / 4096;  // 196
    const int gb  = (N + 63) / 64;      // 782
    const int ngth = (N * 16 + 255) / 256;

    hipMemsetAsync(bcnt, 0, (size_t)NBUCK * 4, stream);
    hipMemsetAsync(pooled, 0, (size_t)NGRAPH * HDIM * 4, stream);
    k_part<<<nbE, 256, 0, stream>>>(src, dst, bcnt, stage, E);
    k_csr<<<NBUCK, 256, 0, stream>>>(stage, bcnt, degi, dis, off, eadj, N);

    // layer 1: split-K x2 (y=0 -> hA, y=1 -> hB), then hA += hB
    k_gemm1<<<dim3(gb, 2), 256, 0, stream>>>(x, W1, hA, N);
    k_sum<<<(N * HDIM / 4 + 255) / 256, 256, 0, stream>>>((float4*)hA, (const float4*)hB,
                                                          N * HDIM / 4);
    k_gather<<<ngth, 256, 0, stream>>>(hA, off, degi, eadj, dis, b1, hB, N);
    // layer 2
    k_gemm2<<<gb, 256, 0, stream>>>(hB, W2, hA, N, 1);
    k_gather<<<ngth, 256, 0, stream>>>(hA, off, degi, eadj, dis, b2, hB, N);
    // layer 3
    k_gemm2<<<gb, 256, 0, stream>>>(hB, W3, hA, N, 1);
    k_gather<<<ngth, 256, 0, stream>>>(hA, off, degi, eadj, dis, b3, hB, N);
    // pool + head
    k_pool_acc<<<NGRAPH * 8, 256, 0, stream>>>(hB, batch, pooled, N);
    k_head<<<1, 640, 0, stream>>>(pooled, batch, linW, linb, out, N);
}